// Round 5
// baseline (173.619 us; speedup 1.0000x reference)
//
#include <hip/hip_runtime.h>
#include <hip/hip_bf16.h>

typedef __attribute__((ext_vector_type(4))) float   f32x4;
typedef __attribute__((ext_vector_type(8))) __bf16  bf16x8;
typedef __attribute__((ext_vector_type(4))) __bf16  bf16x4;

#define NB 4
#define SS 2048
#define DD 1024

__device__ __forceinline__ void gload_lds16(const void* g, void* l) {
  __builtin_amdgcn_global_load_lds((const __attribute__((address_space(1))) void*)g,
                                   (__attribute__((address_space(3))) void*)l,
                                   16, 0, 0);
}

// W[k][n] fp32 -> Wt[n][k] bf16 (transpose+convert); also copy biases. grid (32,32,3) x 256
__global__ __launch_bounds__(256) void prep_w_kernel(
    const float* __restrict__ wq, const float* __restrict__ wk, const float* __restrict__ wv,
    const float* __restrict__ bq, const float* __restrict__ bk, const float* __restrict__ bv,
    __bf16* __restrict__ Wt, float* __restrict__ biasbuf)
{
  const int z = blockIdx.z;
  const float* W  = z == 0 ? wq : (z == 1 ? wk : wv);
  const float* bi = z == 0 ? bq : (z == 1 ? bk : bv);
  __bf16* dst = Wt + (size_t)z * (size_t)(DD * DD);
  const int n0 = blockIdx.x * 32, k0 = blockIdx.y * 32;
  __shared__ float t[32][33];
  const int tx = threadIdx.x & 31, ty = threadIdx.x >> 5;
  #pragma unroll
  for (int i = 0; i < 4; i++)
    t[ty + 8 * i][tx] = W[(size_t)(k0 + ty + 8 * i) * DD + n0 + tx];
  __syncthreads();
  #pragma unroll
  for (int i = 0; i < 4; i++)
    dst[(size_t)(n0 + ty + 8 * i) * DD + k0 + tx] = (__bf16)t[tx][ty + 8 * i];
  if (blockIdx.x == 0 && blockIdx.y == 0) {
    #pragma unroll
    for (int i = 0; i < 4; i++)
      biasbuf[z * DD + threadIdx.x + 256 * i] = bi[threadIdx.x + 256 * i];
  }
}

// ---------------------------------------------------------------------------
// Projection kernel: [8192,1024](bf16) = X(fp32) @ Wt^T + bias, z = q/k/v.
// A staged as FP32 via global_load_lds (4x16B), cvt->bf16 at fragment read.
// B staged bf16 via global_load_lds. z==2 writes V transposed: Vt[b][d][s].
// 128x256 tile, BK=64, 8 waves (2M x 4N), 4-phase counted-vmcnt schedule.
// LDS: A32 2buf x 32KB @0; B 2buf x 2NH x 16KB @65536. Total 128 KiB.
// ---------------------------------------------------------------------------

#define A32_OFF(BUF)     ((BUF) * 32768)
#define B2_OFF(BUF, NH)  (65536 + ((BUF)*2 + (NH)) * 16384)

#define DSREAD_B2(DST, BUF, NH)                                                 \
  _Pragma("unroll") for (int ni = 0; ni < 2; ++ni) {                            \
    _Pragma("unroll") for (int ks = 0; ks < 2; ++ks)                            \
      DST[ni][ks] = *(const bf16x8*)(smem + B2_OFF(BUF, NH) + brb2[ks] + ni * 2048); }

// A: fp32 [128 rows][256B] swizzled image -> bf16x8 fragments
#define DSREAD_A32(BUF)                                                         \
  _Pragma("unroll") for (int mi = 0; mi < 4; ++mi) {                            \
    _Pragma("unroll") for (int ks = 0; ks < 2; ++ks) {                          \
      f32x4 u_ = *(const f32x4*)(smem + A32_OFF(BUF) + a32lo[ks] + mi * 4096);  \
      f32x4 v_ = *(const f32x4*)(smem + A32_OFF(BUF) + a32hi[ks] + mi * 4096);  \
      bf16x8 r_;                                                                \
      r_[0]=(__bf16)u_[0]; r_[1]=(__bf16)u_[1]; r_[2]=(__bf16)u_[2]; r_[3]=(__bf16)u_[3]; \
      r_[4]=(__bf16)v_[0]; r_[5]=(__bf16)v_[1]; r_[6]=(__bf16)v_[2]; r_[7]=(__bf16)v_[3]; \
      af[mi][ks] = r_; } }

// SA bundle: A fp32 (4 issues) + B-half0 (2 issues) = 6 loads
#define PJ_SA(BUF, T) do { int t_ = (T); if (t_ >= 16) t_ = 0;                  \
  const float* gA_ = Ablk + (size_t)t_ * 64;                                    \
  gload_lds16(gA_ + aof0, smem + A32_OFF(BUF) + tid * 16);                      \
  gload_lds16(gA_ + aof1, smem + A32_OFF(BUF) + 8192 + tid * 16);               \
  gload_lds16(gA_ + aof2, smem + A32_OFF(BUF) + 16384 + tid * 16);              \
  gload_lds16(gA_ + aof3, smem + A32_OFF(BUF) + 24576 + tid * 16);              \
  const __bf16* gB_ = Bblk + (size_t)t_ * 64;                                   \
  gload_lds16(gB_ + boff0, smem + B2_OFF(BUF, 0) + tid * 16);                   \
  gload_lds16(gB_ + boff1, smem + B2_OFF(BUF, 0) + 8192 + tid * 16); } while (0)

// SB bundle: B-half1 (2 issues)
#define PJ_SB(BUF, T) do { int t_ = (T); if (t_ >= 16) t_ = 0;                  \
  const __bf16* gB_ = Bblk + (size_t)(128 * 1024) + (size_t)t_ * 64;            \
  gload_lds16(gB_ + boff0, smem + B2_OFF(BUF, 1) + tid * 16);                   \
  gload_lds16(gB_ + boff1, smem + B2_OFF(BUF, 1) + 8192 + tid * 16); } while (0)

#define PJ_MFMA(BF, NH) do {                                                    \
  __builtin_amdgcn_s_barrier();                                                 \
  asm volatile("s_waitcnt lgkmcnt(0)" ::: "memory");                            \
  __builtin_amdgcn_sched_barrier(0);                                            \
  __builtin_amdgcn_s_setprio(1);                                                \
  _Pragma("unroll") for (int mi = 0; mi < 4; ++mi)                              \
  _Pragma("unroll") for (int ni = 0; ni < 2; ++ni)                              \
  _Pragma("unroll") for (int ks = 0; ks < 2; ++ks)                              \
    acc[mi][(NH)*2+ni] = __builtin_amdgcn_mfma_f32_16x16x32_bf16(               \
        af[mi][ks], BF[ni][ks], acc[mi][(NH)*2+ni], 0, 0, 0);                   \
  __builtin_amdgcn_s_setprio(0);                                                \
  __builtin_amdgcn_sched_barrier(0);                                            \
  __builtin_amdgcn_s_barrier(); } while (0)

__global__ __launch_bounds__(512) void proj_kernel(
    const float* __restrict__ Xq, const float* __restrict__ Xk, const float* __restrict__ Xv,
    const __bf16* __restrict__ Wt, const float* __restrict__ bias,
    __bf16* __restrict__ Qo, __bf16* __restrict__ Ko, __bf16* __restrict__ Vt)
{
  extern __shared__ char smem[];

  const int gx = gridDim.x, gy = gridDim.y;
  const int nwg = gx * gy * gridDim.z;
  int lin = blockIdx.x + gx * (blockIdx.y + gy * blockIdx.z);
  const int cpx = nwg >> 3;
  int swz = (lin & 7) * cpx + (lin >> 3);
  const int bx = swz % gx;
  int rem = swz / gx;
  const int by = rem % gy;
  const int bz = rem / gy;

  const long brow = (long)by * 128, bcol = (long)bx * 256;
  const float* Xsel = bz == 0 ? Xq : (bz == 1 ? Xk : Xv);
  const float* Ablk = Xsel + (size_t)brow * 1024;
  const __bf16* Bblk = Wt + (size_t)bz * (DD * DD) + (size_t)bcol * 1024;

  const int tid  = threadIdx.x;
  const int lane = tid & 63;
  const int wid  = tid >> 6;
  const int wm = wid >> 2, wn = wid & 3;
  const int l15 = lane & 15, l4 = lane >> 4;
  const int lx = (lane & 7) << 4;

  // A fp32 staging source offsets (inverse-swizzled), region [128 rows][256B]
  int aof0, aof1, aof2, aof3;
  #pragma unroll
  for (int i = 0; i < 4; ++i) {
    const int p = i * 8192 + tid * 16;
    const int r = p >> 8;
    const int kb = (p ^ ((r & 7) << 4)) & 255;
    const int off = r * 1024 + (kb >> 2);
    if (i == 0) aof0 = off; else if (i == 1) aof1 = off;
    else if (i == 2) aof2 = off; else aof3 = off;
  }
  // B bf16 staging source offsets, region [128 rows][128B]
  int boff0, boff1;
  #pragma unroll
  for (int i = 0; i < 2; ++i) {
    const int p = i * 8192 + tid * 16;
    const int r = p >> 7;
    const int kb = (p ^ ((r & 7) << 4)) & 127;
    const int off = r * 1024 + (kb >> 1);
    if (i == 0) boff0 = off; else boff1 = off;
  }

  // A fragment read offsets (fp32 image, swizzled): row = wm*64+l15 (+16*mi)
  int a32lo[2], a32hi[2];
  #pragma unroll
  for (int ks = 0; ks < 2; ++ks) {
    const int rowb = (wm * 64 + l15) * 256;
    a32lo[ks] = rowb + ((l4 * 32 + ks * 128) ^ lx);
    a32hi[ks] = rowb + ((l4 * 32 + ks * 128 + 16) ^ lx);
  }
  int brb2[2];
  #pragma unroll
  for (int ks = 0; ks < 2; ++ks)
    brb2[ks] = ((((wn * 32 + l15) * 64 + l4 * 8) * 2) + ks * 64) ^ lx;

  f32x4 acc[4][4] = {};
  bf16x8 af[4][2], b0[2][2], b1[2][2];

  // prologue: buf0 full (8), buf1 SA (6) -> 14 outstanding; drain buf0
  PJ_SA(0, 0); PJ_SB(0, 0); PJ_SA(1, 1);
  asm volatile("s_waitcnt vmcnt(6)" ::: "memory");
  __builtin_amdgcn_s_barrier();

  for (int it = 0; it < 8; ++it) {
    const int tt = it * 2;
    // P1: read buf0 {A,B0}(tt); issue SB->buf1(tt+1)
    PJ_SB(1, tt + 1);
    asm volatile("s_waitcnt vmcnt(10)" ::: "memory");
    DSREAD_A32(0); DSREAD_B2(b0, 0, 0);
    PJ_MFMA(b0, 0);
    // P2: read buf0 {B1}(tt); issue SA->buf0(tt+2)
    PJ_SA(0, tt + 2);
    asm volatile("s_waitcnt vmcnt(14)" ::: "memory");
    DSREAD_B2(b1, 0, 1);
    PJ_MFMA(b1, 1);
    // P3: read buf1 {A,B0}(tt+1); issue SB->buf0(tt+2)
    PJ_SB(0, tt + 2);
    asm volatile("s_waitcnt vmcnt(10)" ::: "memory");
    DSREAD_A32(1); DSREAD_B2(b0, 1, 0);
    PJ_MFMA(b0, 0);
    // P4: read buf1 {B1}(tt+1); issue SA->buf1(tt+3)
    PJ_SA(1, tt + 3);
    asm volatile("s_waitcnt vmcnt(14)" ::: "memory");
    DSREAD_B2(b1, 1, 1);
    PJ_MFMA(b1, 1);
  }

  // epilogue
  if (bz == 2) {
    #pragma unroll
    for (int mi = 0; mi < 4; ++mi) {
      #pragma unroll
      for (int n = 0; n < 4; ++n) {
        const long row = brow + wm * 64 + mi * 16 + l4 * 4;
        const long col = bcol + (n >> 1) * 128 + wn * 32 + (n & 1) * 16 + l15;
        const float bvv = bias[2 * DD + col];
        const long bb = row >> 11, s = row & 2047;
        bf16x4 pk = { (__bf16)(acc[mi][n][0] + bvv), (__bf16)(acc[mi][n][1] + bvv),
                      (__bf16)(acc[mi][n][2] + bvv), (__bf16)(acc[mi][n][3] + bvv) };
        *(bf16x4*)&Vt[bb * 2097152 + col * 2048 + s] = pk;
      }
    }
  } else {
    __bf16* C = bz == 0 ? Qo : Ko;
    #pragma unroll
    for (int mi = 0; mi < 4; ++mi) {
      #pragma unroll
      for (int n = 0; n < 4; ++n) {
        const long row = brow + wm * 64 + mi * 16 + l4 * 4;
        const long col = bcol + (n >> 1) * 128 + wn * 32 + (n & 1) * 16 + l15;
        const float bvv = bias[bz * DD + col];
        #pragma unroll
        for (int e = 0; e < 4; ++e)
          C[(row + e) * 1024 + col] = (__bf16)(acc[mi][n][e] + bvv);
      }
    }
  }
}

// ---------------------------------------------------------------------------
// 256x256 8-phase counted-vmcnt GEMM (scores): P = exp(Q @ K^T * scale) -> bf16
// ---------------------------------------------------------------------------

#define A_OFF(BUF, MH) (((BUF)*2 + (MH)) * 16384)
#define B_OFF(BUF, NH) (65536 + ((BUF)*2 + (NH)) * 16384)

#define STAGE_A(BUF, MH, T) do { int t_ = (T); if (t_ >= NT) t_ = 0;            \
  const __bf16* gs_ = Ablk + (size_t)(MH) * (64 * (size_t)lda) + (size_t)t_ * 64; \
  gload_lds16(gs_ + aoff0, smem + A_OFF(BUF, MH) + tid * 16);                    \
  gload_lds16(gs_ + aoff1, smem + A_OFF(BUF, MH) + 8192 + tid * 16); } while (0)

#define STAGE_B(BUF, NH, T) do { int t_ = (T); if (t_ >= NT) t_ = 0;            \
  const __bf16* gs_ = Bblk + (size_t)(NH) * (32 * (size_t)ldb) + (size_t)t_ * 64; \
  gload_lds16(gs_ + boff0, smem + B_OFF(BUF, NH) + tid * 16);                    \
  gload_lds16(gs_ + boff1, smem + B_OFF(BUF, NH) + 8192 + tid * 16); } while (0)

#define DSREAD_A(DST, BUF, MH)                                                  \
  _Pragma("unroll") for (int mi = 0; mi < 4; ++mi) {                            \
    _Pragma("unroll") for (int ks = 0; ks < 2; ++ks)                            \
      DST[mi][ks] = *(const bf16x8*)(smem + A_OFF(BUF, MH) + arb[ks] + mi * 2048); }

#define DSREAD_BS(DST, BUF, NH)                                                 \
  _Pragma("unroll") for (int ni = 0; ni < 2; ++ni) {                            \
    _Pragma("unroll") for (int ks = 0; ks < 2; ++ks)                            \
      DST[ni][ks] = *(const bf16x8*)(smem + B_OFF(BUF, NH) + brb[ks] + ni * 2048); }

#define BARRIER_MFMA(AF, BF, MH, NH) do {                                       \
  __builtin_amdgcn_s_barrier();                                                 \
  asm volatile("s_waitcnt lgkmcnt(0)" ::: "memory");                            \
  __builtin_amdgcn_sched_barrier(0);                                            \
  __builtin_amdgcn_s_setprio(1);                                                \
  _Pragma("unroll") for (int mi = 0; mi < 4; ++mi)                              \
  _Pragma("unroll") for (int ni = 0; ni < 2; ++ni)                              \
  _Pragma("unroll") for (int ks = 0; ks < 2; ++ks)                              \
    acc[(MH)*4+mi][(NH)*2+ni] = __builtin_amdgcn_mfma_f32_16x16x32_bf16(        \
        AF[mi][ks], BF[ni][ks], acc[(MH)*4+mi][(NH)*2+ni], 0, 0, 0);            \
  __builtin_amdgcn_s_setprio(0);                                                \
  __builtin_amdgcn_sched_barrier(0);                                            \
  __builtin_amdgcn_s_barrier(); } while (0)

__global__ __launch_bounds__(512) void gemm8p_kernel(
    const __bf16* __restrict__ A, const __bf16* __restrict__ B,
    float scale, void* __restrict__ Cout,
    int K, int lda, int ldb, int ldc,
    long strideA, long strideB, long strideC)
{
  extern __shared__ char smem[];

  const int gx = gridDim.x, gy = gridDim.y;
  const int nwg = gx * gy * gridDim.z;
  int lin = blockIdx.x + gx * (blockIdx.y + gy * blockIdx.z);
  const int cpx = nwg >> 3;
  int swz = (lin & 7) * cpx + (lin >> 3);
  const int bx = swz % gx;
  int rem = swz / gx;
  const int by = rem % gy;
  const int bz = rem / gy;

  const long brow = (long)by * 256, bcol = (long)bx * 256;
  const __bf16* Ablk = A + (size_t)bz * strideA + (size_t)brow * lda;
  const __bf16* Bblk = B + (size_t)bz * strideB + (size_t)bcol * ldb;

  const int tid  = threadIdx.x;
  const int lane = tid & 63;
  const int wid  = tid >> 6;
  const int wm = wid >> 2, wn = wid & 3;
  const int l15 = lane & 15, l4 = lane >> 4;
  const int lx = (lane & 7) << 4;

  const int NT = K >> 6;
  const int niter = NT >> 1;

  int aoff0, aoff1, boff0, boff1;
  #pragma unroll
  for (int i = 0; i < 2; ++i) {
    const int p = i * 8192 + tid * 16;
    const int l = p ^ (((p >> 7) & 7) << 4);
    const int r = p >> 7;
    const int kb = l & 127;
    const int av = ((r >> 6) * 128 + (r & 63)) * lda + (kb >> 1);
    const int bv = ((r >> 5) * 64 + (r & 31)) * ldb + (kb >> 1);
    if (i == 0) { aoff0 = av; boff0 = bv; } else { aoff1 = av; boff1 = bv; }
  }

  int arb[2], brb[2];
  #pragma unroll
  for (int ks = 0; ks < 2; ++ks) {
    arb[ks] = ((((wm * 64 + l15) * 64 + l4 * 8) * 2) + ks * 64) ^ lx;
    brb[ks] = ((((wn * 32 + l15) * 64 + l4 * 8) * 2) + ks * 64) ^ lx;
  }

  f32x4 acc[8][4] = {};
  bf16x8 a0[4][2], a1[4][2], b0[2][2], b1[2][2];

  STAGE_B(0, 0, 0); STAGE_A(0, 0, 0); STAGE_A(0, 1, 0); STAGE_B(0, 1, 0);
  STAGE_B(1, 0, 1); STAGE_A(1, 0, 1);
  asm volatile("s_waitcnt vmcnt(4)" ::: "memory");
  __builtin_amdgcn_s_barrier();

  for (int it = 0; it < niter; ++it) {
    const int tt = it * 2;
    DSREAD_A(a0, 0, 0); DSREAD_BS(b0, 0, 0);
    STAGE_A(1, 1, tt + 1);
    BARRIER_MFMA(a0, b0, 0, 0);
    DSREAD_A(a1, 0, 1);
    STAGE_B(1, 1, tt + 1);
    BARRIER_MFMA(a1, b0, 1, 0);
    DSREAD_BS(b1, 0, 1);
    STAGE_B(0, 0, tt + 2);
    BARRIER_MFMA(a0, b1, 0, 1);
    STAGE_A(0, 0, tt + 2);
    asm volatile("s_waitcnt vmcnt(4)" ::: "memory");
    BARRIER_MFMA(a1, b1, 1, 1);
    DSREAD_A(a0, 1, 0); DSREAD_BS(b0, 1, 0);
    STAGE_A(0, 1, tt + 2);
    BARRIER_MFMA(a0, b0, 0, 0);
    DSREAD_A(a1, 1, 1);
    STAGE_B(0, 1, tt + 2);
    BARRIER_MFMA(a1, b0, 1, 0);
    DSREAD_BS(b1, 1, 1);
    STAGE_B(1, 0, tt + 3);
    BARRIER_MFMA(a0, b1, 0, 1);
    STAGE_A(1, 0, tt + 3);
    asm volatile("s_waitcnt vmcnt(4)" ::: "memory");
    BARRIER_MFMA(a1, b1, 1, 1);
  }

  const int cr = l4 * 4;
  __bf16* C = (__bf16*)Cout + (size_t)bz * strideC;
  #pragma unroll
  for (int m = 0; m < 8; ++m) {
    #pragma unroll
    for (int n = 0; n < 4; ++n) {
      const long row = brow + wm * 128 + m * 16 + cr;
      const long col = bcol + wn * 64 + n * 16 + l15;
      #pragma unroll
      for (int e = 0; e < 4; ++e)
        C[(row + e) * (size_t)ldc + col] = (__bf16)__expf(acc[m][n][e] * scale);
    }
  }
}

// ---------------------------------------------------------------------------
// 128x256 4-phase counted-vmcnt GEMM (PV): out = (P @ Vt^T) / rowsum(P) -> fp32
// ---------------------------------------------------------------------------

#define PV_A_OFF(BUF)     ((BUF) * 16384)
#define PV_B_OFF(BUF, NH) (32768 + ((BUF)*2 + (NH)) * 16384)

#define PV_DSA(BUF)                                                             \
  _Pragma("unroll") for (int mi = 0; mi < 4; ++mi) {                            \
    _Pragma("unroll") for (int ks = 0; ks < 2; ++ks)                            \
      af[mi][ks] = *(const bf16x8*)(smem + PV_A_OFF(BUF) + ara[ks] + mi * 2048); }

#define PV_DSB(DST, BUF, NH)                                                    \
  _Pragma("unroll") for (int ni = 0; ni < 2; ++ni) {                            \
    _Pragma("unroll") for (int ks = 0; ks < 2; ++ks)                            \
      DST[ni][ks] = *(const bf16x8*)(smem + PV_B_OFF(BUF, NH) + brb2[ks] + ni * 2048); }

#define PV_SA(BUF, T) do { int t_ = (T); if (t_ >= NT) t_ = 0;                  \
  const __bf16* gA_ = Ablk + (size_t)t_ * 64;                                   \
  gload_lds16(gA_ + aoff0, smem + PV_A_OFF(BUF) + tid * 16);                    \
  gload_lds16(gA_ + aoff1, smem + PV_A_OFF(BUF) + 8192 + tid * 16);             \
  const __bf16* gB_ = Bblk + (size_t)t_ * 64;                                   \
  gload_lds16(gB_ + boff0, smem + PV_B_OFF(BUF, 0) + tid * 16);                 \
  gload_lds16(gB_ + boff1, smem + PV_B_OFF(BUF, 0) + 8192 + tid * 16); } while (0)

#define PV_SB(BUF, T) do { int t_ = (T); if (t_ >= NT) t_ = 0;                  \
  const __bf16* gB_ = Bblk + (size_t)(128 * (size_t)ldb) + (size_t)t_ * 64;     \
  gload_lds16(gB_ + boff0, smem + PV_B_OFF(BUF, 1) + tid * 16);                 \
  gload_lds16(gB_ + boff1, smem + PV_B_OFF(BUF, 1) + 8192 + tid * 16); } while (0)

#define PV_MFMA(BF, NH, DOSUM) do {                                             \
  __builtin_amdgcn_s_barrier();                                                 \
  asm volatile("s_waitcnt lgkmcnt(0)" ::: "memory");                            \
  __builtin_amdgcn_sched_barrier(0);                                            \
  __builtin_amdgcn_s_setprio(1);                                                \
  _Pragma("unroll") for (int mi = 0; mi < 4; ++mi)                              \
  _Pragma("unroll") for (int ni = 0; ni < 2; ++ni)                              \
  _Pragma("unroll") for (int ks = 0; ks < 2; ++ks)                              \
    acc[mi][(NH)*2+ni] = __builtin_amdgcn_mfma_f32_16x16x32_bf16(               \
        af[mi][ks], BF[ni][ks], acc[mi][(NH)*2+ni], 0, 0, 0);                   \
  if (DOSUM) {                                                                  \
    _Pragma("unroll") for (int mi = 0; mi < 4; ++mi)                            \
    _Pragma("unroll") for (int ks = 0; ks < 2; ++ks)                            \
      accs[mi] = __builtin_amdgcn_mfma_f32_16x16x32_bf16(                       \
          af[mi][ks], onesf, accs[mi], 0, 0, 0); }                              \
  __builtin_amdgcn_s_setprio(0);                                                \
  __builtin_amdgcn_sched_barrier(0);                                            \
  __builtin_amdgcn_s_barrier(); } while (0)

__global__ __launch_bounds__(512) void gemm128_kernel(
    const __bf16* __restrict__ A, const __bf16* __restrict__ B,
    void* __restrict__ Cout,
    int K, int lda, int ldb, int ldc,
    long strideA, long strideB, long strideC)
{
  extern __shared__ char smem[];

  const int gx = gridDim.x, gy = gridDim.y;
  const int nwg = gx * gy * gridDim.z;
  int lin = blockIdx.x + gx * (blockIdx.y + gy * blockIdx.z);
  const int cpx = nwg >> 3;
  int swz = (lin & 7) * cpx + (lin >> 3);
  const int bx = swz % gx;
  int rem = swz / gx;
  const int by = rem % gy;
  const int bz = rem / gy;

  const long brow = (long)by * 128, bcol = (long)bx * 256;
  const __bf16* Ablk = A + (size_t)bz * strideA + (size_t)brow * lda;
  const __bf16* Bblk = B + (size_t)bz * strideB + (size_t)bcol * ldb;

  const int tid  = threadIdx.x;
  const int lane = tid & 63;
  const int wid  = tid >> 6;
  const int wm = wid >> 2, wn = wid & 3;
  const int l15 = lane & 15, l4 = lane >> 4;
  const int lx = (lane & 7) << 4;

  const int NT = K >> 6;
  const int niter = NT >> 1;

  int aoff0, aoff1, boff0, boff1;
  #pragma unroll
  for (int i = 0; i < 2; ++i) {
    const int p = i * 8192 + tid * 16;
    const int r = p >> 7;
    const int kb = (p ^ ((r & 7) << 4)) & 127;
    const int av = r * lda + (kb >> 1);
    const int bv = r * ldb + (kb >> 1);
    if (i == 0) { aoff0 = av; boff0 = bv; } else { aoff1 = av; boff1 = bv; }
  }

  int ara[2], brb2[2];
  #pragma unroll
  for (int ks = 0; ks < 2; ++ks) {
    ara[ks]  = ((((wm * 64 + l15) * 64 + l4 * 8) * 2) + ks * 64) ^ lx;
    brb2[ks] = ((((wn * 32 + l15) * 64 + l4 * 8) * 2) + ks * 64) ^ lx;
  }

  f32x4 acc[4][4] = {};
  f32x4 accs[4] = {};
  bf16x8 af[4][2], b0[2][2], b1[2][2];
  bf16x8 onesf;
  #pragma unroll
  for (int j = 0; j < 8; ++j) onesf[j] = (__bf16)1.0f;

  PV_SA(0, 0); PV_SB(0, 0); PV_SA(1, 1);
  asm volatile("s_waitcnt vmcnt(6)" ::: "memory");
  __builtin_amdgcn_s_barrier();

  for (int it = 0; it < niter; ++it) {
    const int tt = it * 2;
    PV_SB(1, tt + 1);
    asm volatile("s_waitcnt vmcnt(6)" ::: "memory");
    PV_DSA(0); PV_DSB(b0, 0, 0);
    PV_MFMA(b0, 0, 1);
    PV_SA(0, tt + 2);
    asm volatile("s_waitcnt vmcnt(6)" ::: "memory");
    PV_DSB(b1, 0, 1);
    PV_MFMA(b1, 1, 0);
    PV_SB(0, tt + 2);
    asm volatile("s_waitcnt vmcnt(6)" ::: "memory");
    PV_DSA(1); PV_DSB(b0, 1, 0);
    PV_MFMA(b0, 0, 1);
    PV_SA(1, tt + 3);
    asm volatile("s_waitcnt vmcnt(6)" ::: "memory");
    PV_DSB(b1, 1, 1);
    PV_MFMA(b1, 1, 0);
  }

  float* C = (float*)Cout + (size_t)bz * strideC;
  #pragma unroll
  for (int mi = 0; mi < 4; ++mi) {
    f32x4 inv;
    #pragma unroll
    for (int e = 0; e < 4; ++e) inv[e] = 1.0f / accs[mi][e];
    #pragma unroll
    for (int n = 0; n < 4; ++n) {
      const long row = brow + wm * 64 + mi * 16 + l4 * 4;
      const long col = bcol + (n >> 1) * 128 + wn * 32 + (n & 1) * 16 + l15;
      #pragma unroll
      for (int e = 0; e < 4; ++e)
        C[(row + e) * (size_t)ldc + col] = acc[mi][n][e] * inv[e];
    }
  }
}

extern "C" void kernel_launch(void* const* d_in, const int* in_sizes, int n_in,
                              void* d_out, int out_size, void* d_ws, size_t ws_size,
                              hipStream_t stream)
{
  const float* query = (const float*)d_in[0];
  const float* key   = (const float*)d_in[1];
  const float* value = (const float*)d_in[2];
  const float* wq = (const float*)d_in[3];
  const float* bq = (const float*)d_in[4];
  const float* wk = (const float*)d_in[5];
  const float* bk = (const float*)d_in[6];
  const float* wv = (const float*)d_in[7];
  const float* bv = (const float*)d_in[8];

  char* ws = (char*)d_ws;
  __bf16* P       = (__bf16*)(ws + 0);           // 33,554,432 B
  __bf16* Wt      = (__bf16*)(ws + 33554432);    //  6,291,456 B
  float*  biasbuf = (float*)(ws + 39845888);     //     12,288 B
  __bf16* Qb      = (__bf16*)(ws + 39858176);    // 16,777,216 B
  __bf16* Kb      = (__bf16*)(ws + 56635392);    // 16,777,216 B
  __bf16* Vt      = (__bf16*)(ws + 73412608);    // 16,777,216 B (end 90,189,824)

  hipFuncSetAttribute((const void*)proj_kernel,    hipFuncAttributeMaxDynamicSharedMemorySize, 131072);
  hipFuncSetAttribute((const void*)gemm8p_kernel,  hipFuncAttributeMaxDynamicSharedMemorySize, 131072);
  hipFuncSetAttribute((const void*)gemm128_kernel, hipFuncAttributeMaxDynamicSharedMemorySize, 131072);

  dim3 b256(256), b512(512);

  prep_w_kernel<<<dim3(32, 32, 3), b256, 0, stream>>>(wq, wk, wv, bq, bk, bv, Wt, biasbuf);

  // projections (fp32 A staged to LDS, cvt at read; V written transposed), 768 blocks
  proj_kernel<<<dim3(4, 64, 3), b512, 131072, stream>>>(
      query, key, value, Wt, biasbuf, Qb, Kb, Vt);

  // scores: P[b] = exp(Q[b] @ K[b]^T / 32) -> bf16 (unnormalized), 256 blocks
  gemm8p_kernel<<<dim3(8, 8, 4), b512, 131072, stream>>>(
      Qb, Kb, 0.03125f, P,
      1024, 1024, 1024, 2048,
      2097152L, 2097152L, 4194304L);

  // out[b] = (P[b] @ Vt[b]^T) / rowsum(P[b]) -> fp32, 256 blocks
  gemm128_kernel<<<dim3(4, 16, 4), b512, 98304, stream>>>(
      P, Vt, d_out,
      2048, 2048, 2048, 1024,
      4194304L, 2097152L, 2097152L);

  (void)in_sizes; (void)n_in; (void)out_size; (void)ws_size;
}

// Round 6
// 169.088 us; speedup vs baseline: 1.0268x; 1.0268x over previous
//
#include <hip/hip_runtime.h>
#include <hip/hip_bf16.h>

typedef __attribute__((ext_vector_type(4))) float   f32x4;
typedef __attribute__((ext_vector_type(8))) __bf16  bf16x8;
typedef __attribute__((ext_vector_type(4))) __bf16  bf16x4;

#define NB 4
#define SS 2048
#define DD 1024

__device__ __forceinline__ void gload_lds16(const void* g, void* l) {
  __builtin_amdgcn_global_load_lds((const __attribute__((address_space(1))) void*)g,
                                   (__attribute__((address_space(3))) void*)l,
                                   16, 0, 0);
}

// W[k][n] fp32 -> Wt[n][k] bf16 (transpose+convert); also copy biases. grid (32,32,3) x 256
__global__ __launch_bounds__(256) void prep_w_kernel(
    const float* __restrict__ wq, const float* __restrict__ wk, const float* __restrict__ wv,
    const float* __restrict__ bq, const float* __restrict__ bk, const float* __restrict__ bv,
    __bf16* __restrict__ Wt, float* __restrict__ biasbuf)
{
  const int z = blockIdx.z;
  const float* W  = z == 0 ? wq : (z == 1 ? wk : wv);
  const float* bi = z == 0 ? bq : (z == 1 ? bk : bv);
  __bf16* dst = Wt + (size_t)z * (size_t)(DD * DD);
  const int n0 = blockIdx.x * 32, k0 = blockIdx.y * 32;
  __shared__ float t[32][33];
  const int tx = threadIdx.x & 31, ty = threadIdx.x >> 5;
  #pragma unroll
  for (int i = 0; i < 4; i++)
    t[ty + 8 * i][tx] = W[(size_t)(k0 + ty + 8 * i) * DD + n0 + tx];
  __syncthreads();
  #pragma unroll
  for (int i = 0; i < 4; i++)
    dst[(size_t)(n0 + ty + 8 * i) * DD + k0 + tx] = (__bf16)t[tx][ty + 8 * i];
  if (blockIdx.x == 0 && blockIdx.y == 0) {
    #pragma unroll
    for (int i = 0; i < 4; i++)
      biasbuf[z * DD + threadIdx.x + 256 * i] = bi[threadIdx.x + 256 * i];
  }
}

// ---------------------------------------------------------------------------
// Projection kernel: [8192,1024](bf16) = X(fp32) @ Wt^T + bias, z = q/k/v.
// A: fp32 global -> regs (held 2 phases) -> cvt bf16 -> ds_write into the
// standard swizzled bf16 image (counted-vmcnt FIFO keeps B-queue >= 4 deep).
// B: bf16 via global_load_lds. z==2 writes V transposed: Vt[b][d][s].
// 128x256 tile, BK=64, 8 waves (2M x 4N), 4-phase schedule, LDS 96 KiB.
// ---------------------------------------------------------------------------

#define PJ_A_OFF(BUF)     ((BUF) * 16384)
#define PJ_B_OFF(BUF, NH) (32768 + ((BUF)*2 + (NH)) * 16384)

#define PJ_DSA(BUF)                                                             \
  _Pragma("unroll") for (int mi = 0; mi < 4; ++mi) {                            \
    _Pragma("unroll") for (int ks = 0; ks < 2; ++ks)                            \
      af[mi][ks] = *(const bf16x8*)(smem + PJ_A_OFF(BUF) + ara[ks] + mi * 2048); }

#define PJ_DSB(DST, BUF, NH)                                                    \
  _Pragma("unroll") for (int ni = 0; ni < 2; ++ni) {                            \
    _Pragma("unroll") for (int ks = 0; ks < 2; ++ks)                            \
      DST[ni][ks] = *(const bf16x8*)(smem + PJ_B_OFF(BUF, NH) + brb2[ks] + ni * 2048); }

#define PJ_GLA(V0, V1, V2, V3, T) do { int t_ = (T); if (t_ >= 16) t_ = 0;      \
  const float* g_ = Ablk + (size_t)t_ * 64;                                     \
  V0 = *(const float4*)(g_ + aoffF0); V1 = *(const float4*)(g_ + aoffF0 + 4);   \
  V2 = *(const float4*)(g_ + aoffF1); V3 = *(const float4*)(g_ + aoffF1 + 4);   \
  __builtin_amdgcn_sched_barrier(0); } while (0)

#define PJ_WRA(BUF, V0, V1, V2, V3) do {                                        \
  bf16x8 w0_, w1_;                                                              \
  w0_[0]=(__bf16)V0.x; w0_[1]=(__bf16)V0.y; w0_[2]=(__bf16)V0.z; w0_[3]=(__bf16)V0.w; \
  w0_[4]=(__bf16)V1.x; w0_[5]=(__bf16)V1.y; w0_[6]=(__bf16)V1.z; w0_[7]=(__bf16)V1.w; \
  w1_[0]=(__bf16)V2.x; w1_[1]=(__bf16)V2.y; w1_[2]=(__bf16)V2.z; w1_[3]=(__bf16)V2.w; \
  w1_[4]=(__bf16)V3.x; w1_[5]=(__bf16)V3.y; w1_[6]=(__bf16)V3.z; w1_[7]=(__bf16)V3.w; \
  *(bf16x8*)(smem + PJ_A_OFF(BUF) + tid * 16) = w0_;                            \
  *(bf16x8*)(smem + PJ_A_OFF(BUF) + 8192 + tid * 16) = w1_; } while (0)

#define PJ_SB0(BUF, T) do { int t_ = (T); if (t_ >= 16) t_ = 0;                 \
  const __bf16* gB_ = Bblk + (size_t)t_ * 64;                                   \
  gload_lds16(gB_ + boff0, smem + PJ_B_OFF(BUF, 0) + tid * 16);                 \
  gload_lds16(gB_ + boff1, smem + PJ_B_OFF(BUF, 0) + 8192 + tid * 16); } while (0)

#define PJ_SB1(BUF, T) do { int t_ = (T); if (t_ >= 16) t_ = 0;                 \
  const __bf16* gB_ = Bblk + (size_t)(128 * 1024) + (size_t)t_ * 64;            \
  gload_lds16(gB_ + boff0, smem + PJ_B_OFF(BUF, 1) + tid * 16);                 \
  gload_lds16(gB_ + boff1, smem + PJ_B_OFF(BUF, 1) + 8192 + tid * 16); } while (0)

#define PJ_MFMA(BF, NH) do {                                                    \
  __builtin_amdgcn_s_barrier();                                                 \
  asm volatile("s_waitcnt lgkmcnt(0)" ::: "memory");                            \
  __builtin_amdgcn_sched_barrier(0);                                            \
  __builtin_amdgcn_s_setprio(1);                                                \
  _Pragma("unroll") for (int mi = 0; mi < 4; ++mi)                              \
  _Pragma("unroll") for (int ni = 0; ni < 2; ++ni)                              \
  _Pragma("unroll") for (int ks = 0; ks < 2; ++ks)                              \
    acc[mi][(NH)*2+ni] = __builtin_amdgcn_mfma_f32_16x16x32_bf16(               \
        af[mi][ks], BF[ni][ks], acc[mi][(NH)*2+ni], 0, 0, 0);                   \
  __builtin_amdgcn_s_setprio(0);                                                \
  __builtin_amdgcn_sched_barrier(0);                                            \
  __builtin_amdgcn_s_barrier(); } while (0)

__global__ __launch_bounds__(512) void proj_kernel(
    const float* __restrict__ Xq, const float* __restrict__ Xk, const float* __restrict__ Xv,
    const __bf16* __restrict__ Wt, const float* __restrict__ bias,
    __bf16* __restrict__ Qo, __bf16* __restrict__ Ko, __bf16* __restrict__ Vt)
{
  extern __shared__ char smem[];

  const int gx = gridDim.x, gy = gridDim.y;
  const int nwg = gx * gy * gridDim.z;
  int lin = blockIdx.x + gx * (blockIdx.y + gy * blockIdx.z);
  const int cpx = nwg >> 3;
  int swz = (lin & 7) * cpx + (lin >> 3);
  const int bx = swz % gx;
  int rem = swz / gx;
  const int by = rem % gy;
  const int bz = rem / gy;

  const long brow = (long)by * 128, bcol = (long)bx * 256;
  const float* Xsel = bz == 0 ? Xq : (bz == 1 ? Xk : Xv);
  const float* Ablk = Xsel + (size_t)brow * 1024;
  const __bf16* Bblk = Wt + (size_t)bz * (DD * DD) + (size_t)bcol * 1024;

  const int tid  = threadIdx.x;
  const int lane = tid & 63;
  const int wid  = tid >> 6;
  const int wm = wid >> 2, wn = wid & 3;
  const int l15 = lane & 15, l4 = lane >> 4;
  const int lx = (lane & 7) << 4;

  // A fp32 source offsets for the bf16 LDS image (inverse-swizzled):
  // image byte p -> row r = p>>7, k-bytes kb = (p ^ ((r&7)<<4)) & 127;
  // lane loads 8 contiguous fp32 (2 x float4) matching its 16B bf16 slot.
  int aoffF0, aoffF1;
  #pragma unroll
  for (int i = 0; i < 2; ++i) {
    const int p = i * 8192 + tid * 16;
    const int r = p >> 7;
    const int kb = (p ^ ((r & 7) << 4)) & 127;
    const int aF = r * 1024 + (kb >> 1);
    if (i == 0) aoffF0 = aF; else aoffF1 = aF;
  }
  // B bf16 staging source offsets
  int boff0, boff1;
  #pragma unroll
  for (int i = 0; i < 2; ++i) {
    const int p = i * 8192 + tid * 16;
    const int r = p >> 7;
    const int kb = (p ^ ((r & 7) << 4)) & 127;
    const int off = r * 1024 + (kb >> 1);
    if (i == 0) boff0 = off; else boff1 = off;
  }

  int ara[2], brb2[2];
  #pragma unroll
  for (int ks = 0; ks < 2; ++ks) {
    ara[ks]  = ((((wm * 64 + l15) * 64 + l4 * 8) * 2) + ks * 64) ^ lx;
    brb2[ks] = ((((wn * 32 + l15) * 64 + l4 * 8) * 2) + ks * 64) ^ lx;
  }

  f32x4 acc[4][4] = {};
  bf16x8 af[4][2], b0[2][2], b1[2][2];
  float4 La0, La1, La2, La3, Lb0, Lb1, Lb2, Lb3;

  // prologue: glA(0)[4], glA(1)[4], SB0(0)[2], SB1(0)[2], SB0(1)[2] = 14 loads
  PJ_GLA(La0, La1, La2, La3, 0);
  PJ_GLA(Lb0, Lb1, Lb2, Lb3, 1);
  PJ_SB0(0, 0); PJ_SB1(0, 0); PJ_SB0(1, 1);
  asm volatile("s_waitcnt vmcnt(10)" ::: "memory");   // glA(0) landed
  PJ_WRA(0, La0, La1, La2, La3);
  asm volatile("s_waitcnt vmcnt(6)" ::: "memory");    // glA(1) landed
  PJ_WRA(1, Lb0, Lb1, Lb2, Lb3);
  asm volatile("s_waitcnt vmcnt(2) lgkmcnt(0)" ::: "memory"); // SB0(0),SB1(0) landed
  __builtin_amdgcn_s_barrier();

  for (int it = 0; it < 8; ++it) {
    const int tt = it * 2;
    // P1: reads A-buf0(tt), B0-buf0(tt) [both ensured]; issue glA(tt+2), SB1(tt+1)
    PJ_GLA(La0, La1, La2, La3, tt + 2);
    PJ_SB1(1, tt + 1);
    PJ_DSA(0); PJ_DSB(b0, 0, 0);
    PJ_MFMA(b0, 0);
    // P2: reads B1-buf0(tt); issue SB0(tt+2); vmcnt(10) lands SB1(tt)
    PJ_SB0(0, tt + 2);
    asm volatile("s_waitcnt vmcnt(10)" ::: "memory");
    PJ_DSB(b1, 0, 1);
    PJ_MFMA(b1, 1);
    // P3: vmcnt(4) lands glA(tt+2)+SB0(tt+1); write A-buf0; issue glA(tt+3), SB1(tt+2);
    //     reads A-buf1(tt+1), B0-buf1(tt+1)
    asm volatile("s_waitcnt vmcnt(4)" ::: "memory");
    PJ_WRA(0, La0, La1, La2, La3);
    PJ_GLA(Lb0, Lb1, Lb2, Lb3, tt + 3);
    PJ_SB1(0, tt + 2);
    PJ_DSA(1); PJ_DSB(b0, 1, 0);
    PJ_MFMA(b0, 0);
    // P4: issue SB0(tt+3); vmcnt(4) lands SB1(tt+1)+glA(tt+3); write A-buf1;
    //     reads B1-buf1(tt+1)
    PJ_SB0(1, tt + 3);
    asm volatile("s_waitcnt vmcnt(4)" ::: "memory");
    PJ_WRA(1, Lb0, Lb1, Lb2, Lb3);
    PJ_DSB(b1, 1, 1);
    PJ_MFMA(b1, 1);
  }

  // epilogue
  if (bz == 2) {
    #pragma unroll
    for (int mi = 0; mi < 4; ++mi) {
      #pragma unroll
      for (int n = 0; n < 4; ++n) {
        const long row = brow + wm * 64 + mi * 16 + l4 * 4;
        const long col = bcol + (n >> 1) * 128 + wn * 32 + (n & 1) * 16 + l15;
        const float bvv = bias[2 * DD + col];
        const long bb = row >> 11, s = row & 2047;
        bf16x4 pk = { (__bf16)(acc[mi][n][0] + bvv), (__bf16)(acc[mi][n][1] + bvv),
                      (__bf16)(acc[mi][n][2] + bvv), (__bf16)(acc[mi][n][3] + bvv) };
        *(bf16x4*)&Vt[bb * 2097152 + col * 2048 + s] = pk;
      }
    }
  } else {
    __bf16* C = bz == 0 ? Qo : Ko;
    #pragma unroll
    for (int mi = 0; mi < 4; ++mi) {
      #pragma unroll
      for (int n = 0; n < 4; ++n) {
        const long row = brow + wm * 64 + mi * 16 + l4 * 4;
        const long col = bcol + (n >> 1) * 128 + wn * 32 + (n & 1) * 16 + l15;
        const float bvv = bias[bz * DD + col];
        #pragma unroll
        for (int e = 0; e < 4; ++e)
          C[(row + e) * 1024 + col] = (__bf16)(acc[mi][n][e] + bvv);
      }
    }
  }
}

// ---------------------------------------------------------------------------
// 256x256 8-phase counted-vmcnt GEMM (scores): P = exp(Q @ K^T * scale) -> bf16
// ---------------------------------------------------------------------------

#define A_OFF(BUF, MH) (((BUF)*2 + (MH)) * 16384)
#define B_OFF(BUF, NH) (65536 + ((BUF)*2 + (NH)) * 16384)

#define STAGE_A(BUF, MH, T) do { int t_ = (T); if (t_ >= NT) t_ = 0;            \
  const __bf16* gs_ = Ablk + (size_t)(MH) * (64 * (size_t)lda) + (size_t)t_ * 64; \
  gload_lds16(gs_ + aoff0, smem + A_OFF(BUF, MH) + tid * 16);                    \
  gload_lds16(gs_ + aoff1, smem + A_OFF(BUF, MH) + 8192 + tid * 16); } while (0)

#define STAGE_B(BUF, NH, T) do { int t_ = (T); if (t_ >= NT) t_ = 0;            \
  const __bf16* gs_ = Bblk + (size_t)(NH) * (32 * (size_t)ldb) + (size_t)t_ * 64; \
  gload_lds16(gs_ + boff0, smem + B_OFF(BUF, NH) + tid * 16);                    \
  gload_lds16(gs_ + boff1, smem + B_OFF(BUF, NH) + 8192 + tid * 16); } while (0)

#define DSREAD_A(DST, BUF, MH)                                                  \
  _Pragma("unroll") for (int mi = 0; mi < 4; ++mi) {                            \
    _Pragma("unroll") for (int ks = 0; ks < 2; ++ks)                            \
      DST[mi][ks] = *(const bf16x8*)(smem + A_OFF(BUF, MH) + arb[ks] + mi * 2048); }

#define DSREAD_BS(DST, BUF, NH)                                                 \
  _Pragma("unroll") for (int ni = 0; ni < 2; ++ni) {                            \
    _Pragma("unroll") for (int ks = 0; ks < 2; ++ks)                            \
      DST[ni][ks] = *(const bf16x8*)(smem + B_OFF(BUF, NH) + brb[ks] + ni * 2048); }

#define BARRIER_MFMA(AF, BF, MH, NH) do {                                       \
  __builtin_amdgcn_s_barrier();                                                 \
  asm volatile("s_waitcnt lgkmcnt(0)" ::: "memory");                            \
  __builtin_amdgcn_sched_barrier(0);                                            \
  __builtin_amdgcn_s_setprio(1);                                                \
  _Pragma("unroll") for (int mi = 0; mi < 4; ++mi)                              \
  _Pragma("unroll") for (int ni = 0; ni < 2; ++ni)                              \
  _Pragma("unroll") for (int ks = 0; ks < 2; ++ks)                              \
    acc[(MH)*4+mi][(NH)*2+ni] = __builtin_amdgcn_mfma_f32_16x16x32_bf16(        \
        AF[mi][ks], BF[ni][ks], acc[(MH)*4+mi][(NH)*2+ni], 0, 0, 0);            \
  __builtin_amdgcn_s_setprio(0);                                                \
  __builtin_amdgcn_sched_barrier(0);                                            \
  __builtin_amdgcn_s_barrier(); } while (0)

__global__ __launch_bounds__(512) void gemm8p_kernel(
    const __bf16* __restrict__ A, const __bf16* __restrict__ B,
    float scale, void* __restrict__ Cout,
    int K, int lda, int ldb, int ldc,
    long strideA, long strideB, long strideC)
{
  extern __shared__ char smem[];

  const int gx = gridDim.x, gy = gridDim.y;
  const int nwg = gx * gy * gridDim.z;
  int lin = blockIdx.x + gx * (blockIdx.y + gy * blockIdx.z);
  const int cpx = nwg >> 3;
  int swz = (lin & 7) * cpx + (lin >> 3);
  const int bx = swz % gx;
  int rem = swz / gx;
  const int by = rem % gy;
  const int bz = rem / gy;

  const long brow = (long)by * 256, bcol = (long)bx * 256;
  const __bf16* Ablk = A + (size_t)bz * strideA + (size_t)brow * lda;
  const __bf16* Bblk = B + (size_t)bz * strideB + (size_t)bcol * ldb;

  const int tid  = threadIdx.x;
  const int lane = tid & 63;
  const int wid  = tid >> 6;
  const int wm = wid >> 2, wn = wid & 3;
  const int l15 = lane & 15, l4 = lane >> 4;
  const int lx = (lane & 7) << 4;

  const int NT = K >> 6;
  const int niter = NT >> 1;

  int aoff0, aoff1, boff0, boff1;
  #pragma unroll
  for (int i = 0; i < 2; ++i) {
    const int p = i * 8192 + tid * 16;
    const int l = p ^ (((p >> 7) & 7) << 4);
    const int r = p >> 7;
    const int kb = l & 127;
    const int av = ((r >> 6) * 128 + (r & 63)) * lda + (kb >> 1);
    const int bv = ((r >> 5) * 64 + (r & 31)) * ldb + (kb >> 1);
    if (i == 0) { aoff0 = av; boff0 = bv; } else { aoff1 = av; boff1 = bv; }
  }

  int arb[2], brb[2];
  #pragma unroll
  for (int ks = 0; ks < 2; ++ks) {
    arb[ks] = ((((wm * 64 + l15) * 64 + l4 * 8) * 2) + ks * 64) ^ lx;
    brb[ks] = ((((wn * 32 + l15) * 64 + l4 * 8) * 2) + ks * 64) ^ lx;
  }

  f32x4 acc[8][4] = {};
  bf16x8 a0[4][2], a1[4][2], b0[2][2], b1[2][2];

  STAGE_B(0, 0, 0); STAGE_A(0, 0, 0); STAGE_A(0, 1, 0); STAGE_B(0, 1, 0);
  STAGE_B(1, 0, 1); STAGE_A(1, 0, 1);
  asm volatile("s_waitcnt vmcnt(4)" ::: "memory");
  __builtin_amdgcn_s_barrier();

  for (int it = 0; it < niter; ++it) {
    const int tt = it * 2;
    DSREAD_A(a0, 0, 0); DSREAD_BS(b0, 0, 0);
    STAGE_A(1, 1, tt + 1);
    BARRIER_MFMA(a0, b0, 0, 0);
    DSREAD_A(a1, 0, 1);
    STAGE_B(1, 1, tt + 1);
    BARRIER_MFMA(a1, b0, 1, 0);
    DSREAD_BS(b1, 0, 1);
    STAGE_B(0, 0, tt + 2);
    BARRIER_MFMA(a0, b1, 0, 1);
    STAGE_A(0, 0, tt + 2);
    asm volatile("s_waitcnt vmcnt(4)" ::: "memory");
    BARRIER_MFMA(a1, b1, 1, 1);
    DSREAD_A(a0, 1, 0); DSREAD_BS(b0, 1, 0);
    STAGE_A(0, 1, tt + 2);
    BARRIER_MFMA(a0, b0, 0, 0);
    DSREAD_A(a1, 1, 1);
    STAGE_B(0, 1, tt + 2);
    BARRIER_MFMA(a1, b0, 1, 0);
    DSREAD_BS(b1, 1, 1);
    STAGE_B(1, 0, tt + 3);
    BARRIER_MFMA(a0, b1, 0, 1);
    STAGE_A(1, 0, tt + 3);
    asm volatile("s_waitcnt vmcnt(4)" ::: "memory");
    BARRIER_MFMA(a1, b1, 1, 1);
  }

  const int cr = l4 * 4;
  __bf16* C = (__bf16*)Cout + (size_t)bz * strideC;
  #pragma unroll
  for (int m = 0; m < 8; ++m) {
    #pragma unroll
    for (int n = 0; n < 4; ++n) {
      const long row = brow + wm * 128 + m * 16 + cr;
      const long col = bcol + wn * 64 + n * 16 + l15;
      #pragma unroll
      for (int e = 0; e < 4; ++e)
        C[(row + e) * (size_t)ldc + col] = (__bf16)__expf(acc[m][n][e] * scale);
    }
  }
}

// ---------------------------------------------------------------------------
// 128x256 4-phase counted-vmcnt GEMM (PV): out = (P @ Vt^T) / rowsum(P) -> fp32
// ---------------------------------------------------------------------------

#define PV_A_OFF(BUF)     ((BUF) * 16384)
#define PV_B_OFF(BUF, NH) (32768 + ((BUF)*2 + (NH)) * 16384)

#define PV_DSA(BUF)                                                             \
  _Pragma("unroll") for (int mi = 0; mi < 4; ++mi) {                            \
    _Pragma("unroll") for (int ks = 0; ks < 2; ++ks)                            \
      af[mi][ks] = *(const bf16x8*)(smem + PV_A_OFF(BUF) + ara[ks] + mi * 2048); }

#define PV_DSB(DST, BUF, NH)                                                    \
  _Pragma("unroll") for (int ni = 0; ni < 2; ++ni) {                            \
    _Pragma("unroll") for (int ks = 0; ks < 2; ++ks)                            \
      DST[ni][ks] = *(const bf16x8*)(smem + PV_B_OFF(BUF, NH) + brb2[ks] + ni * 2048); }

#define PV_SA(BUF, T) do { int t_ = (T); if (t_ >= NT) t_ = 0;                  \
  const __bf16* gA_ = Ablk + (size_t)t_ * 64;                                   \
  gload_lds16(gA_ + aoff0, smem + PV_A_OFF(BUF) + tid * 16);                    \
  gload_lds16(gA_ + aoff1, smem + PV_A_OFF(BUF) + 8192 + tid * 16);             \
  const __bf16* gB_ = Bblk + (size_t)t_ * 64;                                   \
  gload_lds16(gB_ + boff0, smem + PV_B_OFF(BUF, 0) + tid * 16);                 \
  gload_lds16(gB_ + boff1, smem + PV_B_OFF(BUF, 0) + 8192 + tid * 16); } while (0)

#define PV_SB(BUF, T) do { int t_ = (T); if (t_ >= NT) t_ = 0;                  \
  const __bf16* gB_ = Bblk + (size_t)(128 * (size_t)ldb) + (size_t)t_ * 64;     \
  gload_lds16(gB_ + boff0, smem + PV_B_OFF(BUF, 1) + tid * 16);                 \
  gload_lds16(gB_ + boff1, smem + PV_B_OFF(BUF, 1) + 8192 + tid * 16); } while (0)

#define PV_MFMA(BF, NH, DOSUM) do {                                             \
  __builtin_amdgcn_s_barrier();                                                 \
  asm volatile("s_waitcnt lgkmcnt(0)" ::: "memory");                            \
  __builtin_amdgcn_sched_barrier(0);                                            \
  __builtin_amdgcn_s_setprio(1);                                                \
  _Pragma("unroll") for (int mi = 0; mi < 4; ++mi)                              \
  _Pragma("unroll") for (int ni = 0; ni < 2; ++ni)                              \
  _Pragma("unroll") for (int ks = 0; ks < 2; ++ks)                              \
    acc[mi][(NH)*2+ni] = __builtin_amdgcn_mfma_f32_16x16x32_bf16(               \
        af[mi][ks], BF[ni][ks], acc[mi][(NH)*2+ni], 0, 0, 0);                   \
  if (DOSUM) {                                                                  \
    _Pragma("unroll") for (int mi = 0; mi < 4; ++mi)                            \
    _Pragma("unroll") for (int ks = 0; ks < 2; ++ks)                            \
      accs[mi] = __builtin_amdgcn_mfma_f32_16x16x32_bf16(                       \
          af[mi][ks], onesf, accs[mi], 0, 0, 0); }                              \
  __builtin_amdgcn_s_setprio(0);                                                \
  __builtin_amdgcn_sched_barrier(0);                                            \
  __builtin_amdgcn_s_barrier(); } while (0)

__global__ __launch_bounds__(512) void gemm128_kernel(
    const __bf16* __restrict__ A, const __bf16* __restrict__ B,
    void* __restrict__ Cout,
    int K, int lda, int ldb, int ldc,
    long strideA, long strideB, long strideC)
{
  extern __shared__ char smem[];

  const int gx = gridDim.x, gy = gridDim.y;
  const int nwg = gx * gy * gridDim.z;
  int lin = blockIdx.x + gx * (blockIdx.y + gy * blockIdx.z);
  const int cpx = nwg >> 3;
  int swz = (lin & 7) * cpx + (lin >> 3);
  const int bx = swz % gx;
  int rem = swz / gx;
  const int by = rem % gy;
  const int bz = rem / gy;

  const long brow = (long)by * 128, bcol = (long)bx * 256;
  const __bf16* Ablk = A + (size_t)bz * strideA + (size_t)brow * lda;
  const __bf16* Bblk = B + (size_t)bz * strideB + (size_t)bcol * ldb;

  const int tid  = threadIdx.x;
  const int lane = tid & 63;
  const int wid  = tid >> 6;
  const int wm = wid >> 2, wn = wid & 3;
  const int l15 = lane & 15, l4 = lane >> 4;
  const int lx = (lane & 7) << 4;

  const int NT = K >> 6;
  const int niter = NT >> 1;

  int aoff0, aoff1, boff0, boff1;
  #pragma unroll
  for (int i = 0; i < 2; ++i) {
    const int p = i * 8192 + tid * 16;
    const int r = p >> 7;
    const int kb = (p ^ ((r & 7) << 4)) & 127;
    const int av = r * lda + (kb >> 1);
    const int bv = r * ldb + (kb >> 1);
    if (i == 0) { aoff0 = av; boff0 = bv; } else { aoff1 = av; boff1 = bv; }
  }

  int ara[2], brb2[2];
  #pragma unroll
  for (int ks = 0; ks < 2; ++ks) {
    ara[ks]  = ((((wm * 64 + l15) * 64 + l4 * 8) * 2) + ks * 64) ^ lx;
    brb2[ks] = ((((wn * 32 + l15) * 64 + l4 * 8) * 2) + ks * 64) ^ lx;
  }

  f32x4 acc[4][4] = {};
  f32x4 accs[4] = {};
  bf16x8 af[4][2], b0[2][2], b1[2][2];
  bf16x8 onesf;
  #pragma unroll
  for (int j = 0; j < 8; ++j) onesf[j] = (__bf16)1.0f;

  PV_SA(0, 0); PV_SB(0, 0); PV_SA(1, 1);
  asm volatile("s_waitcnt vmcnt(6)" ::: "memory");
  __builtin_amdgcn_s_barrier();

  for (int it = 0; it < niter; ++it) {
    const int tt = it * 2;
    PV_SB(1, tt + 1);
    asm volatile("s_waitcnt vmcnt(6)" ::: "memory");
    PV_DSA(0); PV_DSB(b0, 0, 0);
    PV_MFMA(b0, 0, 1);
    PV_SA(0, tt + 2);
    asm volatile("s_waitcnt vmcnt(6)" ::: "memory");
    PV_DSB(b1, 0, 1);
    PV_MFMA(b1, 1, 0);
    PV_SB(0, tt + 2);
    asm volatile("s_waitcnt vmcnt(6)" ::: "memory");
    PV_DSA(1); PV_DSB(b0, 1, 0);
    PV_MFMA(b0, 0, 1);
    PV_SA(1, tt + 3);
    asm volatile("s_waitcnt vmcnt(6)" ::: "memory");
    PV_DSB(b1, 1, 1);
    PV_MFMA(b1, 1, 0);
  }

  float* C = (float*)Cout + (size_t)bz * strideC;
  #pragma unroll
  for (int mi = 0; mi < 4; ++mi) {
    f32x4 inv;
    #pragma unroll
    for (int e = 0; e < 4; ++e) inv[e] = 1.0f / accs[mi][e];
    #pragma unroll
    for (int n = 0; n < 4; ++n) {
      const long row = brow + wm * 64 + mi * 16 + l4 * 4;
      const long col = bcol + (n >> 1) * 128 + wn * 32 + (n & 1) * 16 + l15;
      #pragma unroll
      for (int e = 0; e < 4; ++e)
        C[(row + e) * (size_t)ldc + col] = acc[mi][n][e] * inv[e];
    }
  }
}

extern "C" void kernel_launch(void* const* d_in, const int* in_sizes, int n_in,
                              void* d_out, int out_size, void* d_ws, size_t ws_size,
                              hipStream_t stream)
{
  const float* query = (const float*)d_in[0];
  const float* key   = (const float*)d_in[1];
  const float* value = (const float*)d_in[2];
  const float* wq = (const float*)d_in[3];
  const float* bq = (const float*)d_in[4];
  const float* wk = (const float*)d_in[5];
  const float* bk = (const float*)d_in[6];
  const float* wv = (const float*)d_in[7];
  const float* bv = (const float*)d_in[8];

  char* ws = (char*)d_ws;
  __bf16* P       = (__bf16*)(ws + 0);           // 33,554,432 B
  __bf16* Wt      = (__bf16*)(ws + 33554432);    //  6,291,456 B
  float*  biasbuf = (float*)(ws + 39845888);     //     12,288 B
  __bf16* Qb      = (__bf16*)(ws + 39858176);    // 16,777,216 B
  __bf16* Kb      = (__bf16*)(ws + 56635392);    // 16,777,216 B
  __bf16* Vt      = (__bf16*)(ws + 73412608);    // 16,777,216 B (end 90,189,824)

  hipFuncSetAttribute((const void*)proj_kernel,    hipFuncAttributeMaxDynamicSharedMemorySize, 131072);
  hipFuncSetAttribute((const void*)gemm8p_kernel,  hipFuncAttributeMaxDynamicSharedMemorySize, 131072);
  hipFuncSetAttribute((const void*)gemm128_kernel, hipFuncAttributeMaxDynamicSharedMemorySize, 131072);

  dim3 b256(256), b512(512);

  prep_w_kernel<<<dim3(32, 32, 3), b256, 0, stream>>>(wq, wk, wv, bq, bk, bv, Wt, biasbuf);

  // projections (fp32 A reg-staged -> bf16 LDS, counted FIFO; V transposed), 768 blocks
  proj_kernel<<<dim3(4, 64, 3), b512, 98304, stream>>>(
      query, key, value, Wt, biasbuf, Qb, Kb, Vt);

  // scores: P[b] = exp(Q[b] @ K[b]^T / 32) -> bf16 (unnormalized), 256 blocks
  gemm8p_kernel<<<dim3(8, 8, 4), b512, 131072, stream>>>(
      Qb, Kb, 0.03125f, P,
      1024, 1024, 1024, 2048,
      2097152L, 2097152L, 4194304L);

  // out[b] = (P[b] @ Vt[b]^T) / rowsum(P[b]) -> fp32, 256 blocks
  gemm128_kernel<<<dim3(4, 16, 4), b512, 98304, stream>>>(
      P, Vt, d_out,
      2048, 2048, 2048, 1024,
      4194304L, 2097152L, 2097152L);

  (void)in_sizes; (void)n_in; (void)out_size; (void)ws_size;
}